// Round 1
// baseline (390.132 us; speedup 1.0000x reference)
//
#include <hip/hip_runtime.h>

// RNN car-following model: NVEH=16384 vehicles, NT=256 steps, H=20 hidden.
// Strategy: wave = 16 vehicles; z = [h,x,1] @ U_aug via bf16 MFMA 16x16x32
// (K=24 padded to 32). U_aug columns permuted so that MFMA output tiles 0..3
// hold gates i,f,g,o for j=0..15 lane-locally; tile 4 (j=16..19, gate-
// interleaved) redistributed with shfl_xor. fp32 state (pos,speed,c) in regs.

#define NVEH 16384
#define NT   256
#define H    20

typedef float f32x4  __attribute__((ext_vector_type(4)));
typedef short bf16x8 __attribute__((ext_vector_type(8)));
typedef short bf16x4 __attribute__((ext_vector_type(4)));

__device__ __forceinline__ short f2bf(float f) {     // RNE float->bf16
    unsigned u = __builtin_bit_cast(unsigned, f);
    u += 0x7fffu + ((u >> 16) & 1u);
    return (short)(u >> 16);
}
__device__ __forceinline__ float sigf(float x) {
    return __builtin_amdgcn_rcpf(1.f + __expf(-x));
}
__device__ __forceinline__ float tanh_(float x) {
    return 2.f * __builtin_amdgcn_rcpf(1.f + __expf(-2.f * x)) - 1.f;
}
__device__ __forceinline__ float sel4(f32x4 v, int i) {   // v[i], i in 0..3
    float a = (i & 1) ? v[1] : v[0];
    float b = (i & 1) ? v[3] : v[2];
    return (i & 2) ? b : a;
}

__global__ __launch_bounds__(256) void rnncf_kernel(
    const float* __restrict__ lead,   // (NVEH, NT, 2)
    const float* __restrict__ inits,  // (NVEH, 2)  [pos, speed]
    const float* __restrict__ h0,     // (NVEH, H)
    const float* __restrict__ c0,     // (NVEH, H)
    const float* __restrict__ W,      // (3, 80)
    const float* __restrict__ U,      // (20, 80)
    const float* __restrict__ b,      // (80,)
    const float* __restrict__ Wd,     // (20,)
    const float* __restrict__ bd,     // (1,)
    float* __restrict__ out)
{
    // UT: U_aug transposed, bf16, permuted cols: [col'][k], k-stride 1.
    // aug: per-vehicle A rows, 40 bf16 stride (80B; breaks bank conflicts,
    //      keeps 16B alignment). elements: 0..19 h, 20..22 x, 23 = 1, 24..31 = 0.
    __shared__ __attribute__((aligned(16))) short UT[80 * 32];
    __shared__ __attribute__((aligned(16))) short aug[64 * 40];

    const int tid  = threadIdx.x;
    const int wv   = tid >> 6;        // wave 0..3
    const int lane = tid & 63;
    const int quad = lane >> 4;       // 0..3
    const int c    = lane & 15;       // MFMA col within tile / j index
    const int q3   = c & 3;

    // ---- build UT: rows 0..19 = U, 20..22 = W, 23 = b, 24..31 = 0 ----
    // col permutation: col = gate*20 + j ; j<16 -> col' = 16*gate + j (tiles 0-3)
    //                                      j>=16 -> col' = 64 + 4*(j-16) + gate
    for (int idx = tid; idx < 80 * 32; idx += 256) {
        int col = idx >> 5;
        int k   = idx & 31;
        float v;
        if      (k < 20)  v = U[k * 80 + col];
        else if (k < 23)  v = W[(k - 20) * 80 + col];
        else if (k == 23) v = b[col];
        else              v = 0.f;
        int gate = col / 20, j = col - gate * 20;
        int colp = (j < 16) ? (gate * 16 + j) : (64 + 4 * (j - 16) + gate);
        UT[colp * 32 + k] = f2bf(v);
    }

    // ---- init aug: h part from h0, k=24..31 zero ----
    const int vbase = blockIdx.x * 64;
    for (int idx = tid; idx < 64 * H; idx += 256) {
        int vl = idx / H, j = idx - vl * H;
        aug[vl * 40 + j] = f2bf(h0[(vbase + vl) * H + j]);
    }
    for (int idx = tid; idx < 64 * 8; idx += 256) {
        int vl = idx >> 3;
        aug[vl * 40 + 24 + (idx & 7)] = 0;
    }
    __syncthreads();

    // ---- persistent per-lane state ----
    const int wveh0 = wv * 16;            // wave's first local vehicle
    const int gveh0 = vbase + wveh0;      // global vehicle base of wave
    float pos[4], spd[4], cst[4], hl[4];
    for (int r = 0; r < 4; ++r) {
        int gv = gveh0 + quad * 4 + r;
        pos[r] = inits[gv * 2 + 0];
        spd[r] = inits[gv * 2 + 1];
        cst[r] = c0[gv * H + c];          // c-state for (veh r, j=c)
        hl[r]  = 0.f;
    }
    // tile-4 item this lane owns: vehicle quad*4 + q3, j = 16 + (c>>2)
    const int v4l = quad * 4 + q3;
    const int j4  = 16 + (c >> 2);
    float cst4 = c0[(gveh0 + v4l) * H + j4];
    float hl4  = 0.f;
    const float wd_c = Wd[c];
    const float wd_4 = Wd[j4];
    const float bdv  = bd[0];

    // B fragments (loop-invariant): B[k][n], n = c (col within tile), k = quad*8+j
    bf16x8 B[5];
    for (int t5 = 0; t5 < 5; ++t5)
        B[t5] = *(const bf16x8*)&UT[(16 * t5 + c) * 32 + quad * 8];

    // x-writer lanes: c in [4,8) own vehicle quad*4 + (c-4)
    const bool xw = (c >= 4 && c < 8);
    const int  vrx = c - 4;
    const int  ldbase = (gveh0 + quad * 4 + vrx) * (NT * 2);
    float ld0 = 0.f, ld1 = 0.f;
    if (xw) { ld0 = lead[ldbase]; ld1 = lead[ldbase + 1]; }

    const int augrow = (wveh0 + c) * 40;  // this lane's A row (m = c)

    for (int t = 0; t < NT; ++t) {
        // ---- write x (pre-update pos/speed) into aug elements 20..23 ----
        if (xw) {
            float x0 = (ld0 - pos[vrx]) * 0.01f;   // curhd = (lead_pos-pos)/100
            float x1 = spd[vrx] * 0.025f;          // speed/40
            float x2 = ld1 * 0.025f;               // lead_speed/40
            bf16x4 xs = { f2bf(x0), f2bf(x1), f2bf(x2), f2bf(1.f) };
            *(bf16x4*)&aug[(wveh0 + quad * 4 + vrx) * 40 + 20] = xs;
        }
        __syncthreads();

        // ---- A fragment + 5 MFMAs ----
        bf16x8 A = *(const bf16x8*)&aug[augrow + quad * 8];
        f32x4 zero = {0.f, 0.f, 0.f, 0.f};
        f32x4 z0 = __builtin_amdgcn_mfma_f32_16x16x32_bf16(A, B[0], zero, 0, 0, 0);
        f32x4 z1 = __builtin_amdgcn_mfma_f32_16x16x32_bf16(A, B[1], zero, 0, 0, 0);
        f32x4 z2 = __builtin_amdgcn_mfma_f32_16x16x32_bf16(A, B[2], zero, 0, 0, 0);
        f32x4 z3 = __builtin_amdgcn_mfma_f32_16x16x32_bf16(A, B[3], zero, 0, 0, 0);
        f32x4 z4 = __builtin_amdgcn_mfma_f32_16x16x32_bf16(A, B[4], zero, 0, 0, 0);

        // prefetch next step's lead during compute
        if (xw) {
            int tn = (t < NT - 1) ? (t + 1) : t;
            ld0 = lead[ldbase + tn * 2];
            ld1 = lead[ldbase + tn * 2 + 1];
        }

        // ---- elementwise main: (veh quad*4+r, j=c), gates from tiles 0..3 ----
        float contrib[4];
        for (int r = 0; r < 4; ++r) {
            float cc = sigf(z1[r]) * cst[r] + sigf(z0[r]) * tanh_(z2[r]);
            cst[r] = cc;
            float hh = sigf(z3[r]) * tanh_(cc);
            hl[r] = hh;
            contrib[r] = hh * wd_c;
            aug[(wveh0 + quad * 4 + r) * 40 + c] = f2bf(hh);
        }

        // ---- tile 4: gather 4 gates of (veh v4l, j4) via shfl_xor ----
        {
            float sOwn = sel4(z4, q3);
            float s1 = __shfl_xor(sel4(z4, q3 ^ 1), 1);
            float s2 = __shfl_xor(sel4(z4, q3 ^ 2), 2);
            float s3 = __shfl_xor(sel4(z4, q3 ^ 3), 3);
            // gate g arrives via mask m = q3^g
#define PICK(mm) ((mm) == 0 ? sOwn : ((mm) == 1 ? s1 : ((mm) == 2 ? s2 : s3)))
            float zi4 = PICK(q3 ^ 0);
            float zf4 = PICK(q3 ^ 1);
            float zg4 = PICK(q3 ^ 2);
            float zo4 = PICK(q3 ^ 3);
#undef PICK
            float cc4 = sigf(zf4) * cst4 + sigf(zi4) * tanh_(zg4);
            cst4 = cc4;
            float h4 = sigf(zo4) * tanh_(cc4);
            hl4 = h4;
            contrib[q3] += h4 * wd_4;
            aug[(wveh0 + v4l) * 40 + j4] = f2bf(h4);
        }

        // ---- butterfly reduce h@Wd over the quad's 16 lanes ----
        for (int m = 1; m < 16; m <<= 1)
            for (int r = 0; r < 4; ++r)
                contrib[r] += __shfl_xor(contrib[r], m);

        for (int r = 0; r < 4; ++r) {
            float acc = 7.f * (contrib[r] + bdv) - 4.f;  // (MAXA-MINA)*out+MINA
            spd[r] += 0.1f * acc;
            pos[r] += 0.1f * acc;
        }

        // ---- emit pos (lanes 8..11, one vehicle each) ----
        if (c >= 8 && c < 12) {
            int vr = c - 8;
            out[t * NVEH + gveh0 + quad * 4 + vr] = pos[vr];
        }
    }

    // ---- final outputs: speed, h, c ----
    const int oS = NT * NVEH;
    const int oH = oS + NVEH;
    const int oC = oH + NVEH * H;
    if (c >= 8 && c < 12) {
        int vr = c - 8;
        out[oS + gveh0 + quad * 4 + vr] = spd[vr];
    }
    for (int r = 0; r < 4; ++r) {
        int gv = gveh0 + quad * 4 + r;
        out[oH + gv * H + c] = hl[r];
        out[oC + gv * H + c] = cst[r];
    }
    out[oH + (gveh0 + v4l) * H + j4] = hl4;
    out[oC + (gveh0 + v4l) * H + j4] = cst4;
}

extern "C" void kernel_launch(void* const* d_in, const int* in_sizes, int n_in,
                              void* d_out, int out_size, void* d_ws, size_t ws_size,
                              hipStream_t stream) {
    const float* lead  = (const float*)d_in[0];
    const float* inits = (const float*)d_in[1];
    const float* h0    = (const float*)d_in[2];
    const float* c0    = (const float*)d_in[3];
    const float* W     = (const float*)d_in[4];
    const float* U     = (const float*)d_in[5];
    const float* b     = (const float*)d_in[6];
    const float* Wd    = (const float*)d_in[7];
    const float* bd    = (const float*)d_in[8];
    float* out = (float*)d_out;

    rnncf_kernel<<<NVEH / 64, 256, 0, stream>>>(lead, inits, h0, c0, W, U, b, Wd, bd, out);
}

// Round 2
// 362.897 us; speedup vs baseline: 1.0750x; 1.0750x over previous
//
#include <hip/hip_runtime.h>

// RNN car-following model: NVEH=16384, NT=256, H=20.
// R2: 8 vehicles/wave (2048 waves -> 2 waves/SIMD, occupancy 2x), A-row
// permutation pi(v)=4*(v>>1)+(v&1) so quad q's MFMA output regs r=0,1 are
// vehicles 2q,2q+1 -> every lane does 2 main items, no gate exchange.
// No per-step __syncthreads (waves own disjoint aug regions; same-wave DS
// ops are pipeline-ordered). log2(e) folded into weights: trans = raw exp2.

#define NVEH 16384
#define NT   256
#define H    20

typedef float f32x4  __attribute__((ext_vector_type(4)));
typedef short bf16x8 __attribute__((ext_vector_type(8)));
typedef short bf16x4 __attribute__((ext_vector_type(4)));

#if __has_builtin(__builtin_amdgcn_exp2f)
#define EXP2(x) __builtin_amdgcn_exp2f(x)
#else
#define EXP2(x) __expf((x) * 0.69314718056f)
#endif

__device__ __forceinline__ short f2bf(float f) {     // RNE float->bf16
    unsigned u = __builtin_bit_cast(unsigned, f);
    u += 0x7fffu + ((u >> 16) & 1u);
    return (short)(u >> 16);
}
// sigmoid of a pre-scaled (x*log2e) argument: 1/(1+2^-x)
__device__ __forceinline__ float sig2(float x) {
    return __builtin_amdgcn_rcpf(1.f + EXP2(-x));
}
__device__ __forceinline__ float sel4(f32x4 v, int i) {   // v[i], i in 0..3
    float a = (i & 1) ? v[1] : v[0];
    float b = (i & 1) ? v[3] : v[2];
    return (i & 2) ? b : a;
}

__global__ __launch_bounds__(256) void rnncf_kernel(
    const float* __restrict__ lead,   // (NVEH, NT, 2)
    const float* __restrict__ inits,  // (NVEH, 2)
    const float* __restrict__ h0,     // (NVEH, H)
    const float* __restrict__ c0,     // (NVEH, H)
    const float* __restrict__ W,      // (3, 80)
    const float* __restrict__ U,      // (20, 80)
    const float* __restrict__ b,      // (80,)
    const float* __restrict__ Wd,     // (20,)
    const float* __restrict__ bd,     // (1,)
    float* __restrict__ out)
{
    // UT: U_aug^T bf16, permuted cols (tiles 0..3 = gates i/f/g/o for j<16,
    // tile 4 = j=16..19 gate-interleaved), scaled by log2e (2*log2e for g).
    // aug: per-wave 16 rows x 40 shorts; vehicle v at row pi(v)=4*(v>>1)+(v&1),
    // rows {2,3,6,7,10,11,14,15} stay zero forever.
    __shared__ __attribute__((aligned(16))) short UT[80 * 32];
    __shared__ __attribute__((aligned(16))) short aug[4][640];

    const int tid  = threadIdx.x;
    const int wv   = tid >> 6;
    const int lane = tid & 63;
    const int quad = lane >> 4;       // 0..3
    const int c    = lane & 15;       // j index / MFMA col

    const float L2E = 1.44269504f;

    // ---- build UT (block-cooperative) ----
    for (int idx = tid; idx < 80 * 32; idx += 256) {
        int col = idx >> 5;
        int k   = idx & 31;
        float v;
        if      (k < 20)  v = U[k * 80 + col];
        else if (k < 23)  v = W[(k - 20) * 80 + col];
        else if (k == 23) v = b[col];
        else              v = 0.f;
        int gate = col / 20, j = col - gate * 20;
        v *= (gate == 2) ? (2.f * L2E) : L2E;   // g column: 2*log2e for tanh
        int colp = (j < 16) ? (gate * 16 + j) : (64 + 4 * (j - 16) + gate);
        UT[colp * 32 + k] = f2bf(v);
    }

    const int gveh0 = blockIdx.x * 32 + wv * 8;   // wave's first vehicle

    // ---- per-wave aug init: zero all, then fill h rows (same-wave order ok)
    for (int idx = lane; idx < 640; idx += 64) aug[wv][idx] = 0;
    for (int idx = lane; idx < 8 * H; idx += 64) {
        int v8 = idx / H, j = idx - v8 * H;
        int row = 4 * (v8 >> 1) + (v8 & 1);
        aug[wv][row * 40 + j] = f2bf(h0[(gveh0 + v8) * H + j]);
    }
    __syncthreads();   // only for UT visibility; no barriers after this

    // ---- per-lane state: quad q owns vehicles 2q, 2q+1 ----
    float pos[2], spd[2], cst[2], hl[2];
    for (int s = 0; s < 2; ++s) {
        int gv = gveh0 + 2 * quad + s;
        pos[s] = inits[gv * 2 + 0];
        spd[s] = inits[gv * 2 + 1];
        cst[s] = c0[gv * H + c];
        hl[s]  = 0.f;
    }
    // tile-4 item: lanes with (c&3)<2 own (veh 2q+s4, j4=16+(c>>2))
    const int  s4   = c & 3;
    const int  k4   = c >> 2;
    const int  j4   = 16 + k4;
    const bool own4 = s4 < 2;
    float cst4 = own4 ? c0[(gveh0 + 2 * quad + s4) * H + j4] : 0.f;
    float hl4  = 0.f;
    const float wd_c = Wd[c];
    const float wd_4 = Wd[j4];
    const float bdv  = bd[0];

    // B fragments (loop-invariant)
    bf16x8 B[5];
    for (int t5 = 0; t5 < 5; ++t5)
        B[t5] = *(const bf16x8*)&UT[(16 * t5 + c) * 32 + quad * 8];

    // lead stream: lanes c<2 own vehicle 2q+c
    float ld0 = 0.f, ld1 = 0.f;
    long  ldbase = 0;
    if (c < 2) {
        ldbase = (long)(gveh0 + 2 * quad + c) * (NT * 2);
        ld0 = lead[ldbase];
        ld1 = lead[ldbase + 1];
    }

    const int augA = c * 40 + quad * 8;   // A-fragment address (row=c)

    for (int t = 0; t < NT; ++t) {
        // ---- x write (lanes c<2, vehicle 2q+c at row 4q+c) ----
        if (c < 2) {
            float x0 = (ld0 - pos[c]) * 0.01f;   // (lead_pos-pos)/100
            float x1 = spd[c] * 0.025f;          // speed/40
            float x2 = ld1 * 0.025f;             // lead_speed/40
            bf16x4 xs = { f2bf(x0), f2bf(x1), f2bf(x2), f2bf(1.f) };
            *(bf16x4*)&aug[wv][(4 * quad + c) * 40 + 20] = xs;
        }

        // ---- A fragment + 5 MFMAs ----
        bf16x8 A = *(const bf16x8*)&aug[wv][augA];
        f32x4 zero = {0.f, 0.f, 0.f, 0.f};
        f32x4 z0 = __builtin_amdgcn_mfma_f32_16x16x32_bf16(A, B[0], zero, 0, 0, 0);
        f32x4 z1 = __builtin_amdgcn_mfma_f32_16x16x32_bf16(A, B[1], zero, 0, 0, 0);
        f32x4 z2 = __builtin_amdgcn_mfma_f32_16x16x32_bf16(A, B[2], zero, 0, 0, 0);
        f32x4 z3 = __builtin_amdgcn_mfma_f32_16x16x32_bf16(A, B[3], zero, 0, 0, 0);
        f32x4 z4 = __builtin_amdgcn_mfma_f32_16x16x32_bf16(A, B[4], zero, 0, 0, 0);

        // prefetch next lead during compute
        if (c < 2) {
            int tn = (t < NT - 1) ? (t + 1) : t;
            ld0 = lead[ldbase + tn * 2];
            ld1 = lead[ldbase + tn * 2 + 1];
        }

        // ---- main items: (veh 2q+s, j=c) from z regs r=s ----
        float contrib[2];
        for (int s = 0; s < 2; ++s) {
            float cc = sig2(z1[s]) * cst[s]
                     + sig2(z0[s]) * (2.f * sig2(z2[s]) - 1.f);   // tanh(g)
            cst[s] = cc;
            float hh = sig2(z3[s]) * (2.f * sig2(2.f * L2E * cc) - 1.f); // tanh(c)
            hl[s] = hh;
            contrib[s] = hh * wd_c;
            aug[wv][(4 * quad + s) * 40 + c] = f2bf(hh);
        }

        // ---- tile 4: gather 4 gates via intra-4-lane shfl_xor ----
        {
            float sOwn = sel4(z4, s4);
            float v1 = __shfl_xor(sel4(z4, s4 ^ 1), 1);
            float v2 = __shfl_xor(sel4(z4, s4 ^ 2), 2);
            float v3 = __shfl_xor(sel4(z4, s4 ^ 3), 3);
#define PICK(mm) ((mm) == 0 ? sOwn : ((mm) == 1 ? v1 : ((mm) == 2 ? v2 : v3)))
            float zi4 = PICK(s4 ^ 0);
            float zf4 = PICK(s4 ^ 1);
            float zg4 = PICK(s4 ^ 2);
            float zo4 = PICK(s4 ^ 3);
#undef PICK
            float cc4 = sig2(zf4) * cst4 + sig2(zi4) * (2.f * sig2(zg4) - 1.f);
            float h4  = sig2(zo4) * (2.f * sig2(2.f * L2E * cc4) - 1.f);
            if (own4) {
                cst4 = cc4;
                hl4  = h4;
                contrib[s4] += h4 * wd_4;
                aug[wv][(4 * quad + s4) * 40 + j4] = f2bf(h4);
            }
        }

        // ---- butterfly reduce over the quad's 16 lanes (2 regs) ----
        for (int m = 1; m < 16; m <<= 1) {
            contrib[0] += __shfl_xor(contrib[0], m);
            contrib[1] += __shfl_xor(contrib[1], m);
        }

        for (int s = 0; s < 2; ++s) {
            float acc = 7.f * (contrib[s] + bdv) - 4.f;
            spd[s] += 0.1f * acc;
            pos[s] += 0.1f * acc;
        }

        // ---- emit pos (lanes c=2,3 -> vehicles 2q, 2q+1) ----
        if (c == 2 || c == 3)
            out[t * NVEH + gveh0 + 2 * quad + (c - 2)] = pos[c - 2];
    }

    // ---- final outputs: speed, h, c ----
    const int oS = NT * NVEH;
    const int oH = oS + NVEH;
    const int oC = oH + NVEH * H;
    if (c == 2 || c == 3)
        out[oS + gveh0 + 2 * quad + (c - 2)] = spd[c - 2];
    for (int s = 0; s < 2; ++s) {
        int gv = gveh0 + 2 * quad + s;
        out[oH + gv * H + c] = hl[s];
        out[oC + gv * H + c] = cst[s];
    }
    if (own4) {
        int gv = gveh0 + 2 * quad + s4;
        out[oH + gv * H + j4] = hl4;
        out[oC + gv * H + j4] = cst4;
    }
}

extern "C" void kernel_launch(void* const* d_in, const int* in_sizes, int n_in,
                              void* d_out, int out_size, void* d_ws, size_t ws_size,
                              hipStream_t stream) {
    const float* lead  = (const float*)d_in[0];
    const float* inits = (const float*)d_in[1];
    const float* h0    = (const float*)d_in[2];
    const float* c0    = (const float*)d_in[3];
    const float* W     = (const float*)d_in[4];
    const float* U     = (const float*)d_in[5];
    const float* b     = (const float*)d_in[6];
    const float* Wd    = (const float*)d_in[7];
    const float* bd    = (const float*)d_in[8];
    float* out = (float*)d_out;

    rnncf_kernel<<<NVEH / 32, 256, 0, stream>>>(lead, inits, h0, c0, W, U, b, Wd, bd, out);
}

// Round 5
// 294.725 us; speedup vs baseline: 1.3237x; 1.2313x over previous
//
#include <hip/hip_runtime.h>

// RNN car-following: NVEH=16384, NT=256, H=20. 8 veh/wave, MFMA 16x16x32 bf16.
// R5: lagged-x restructuring kept, but acc feedback is now FP32-exact:
//  - tile 5 has 16 IDENTICAL columns bf16(7*Wd) (+bias at k=23) so every lane
//    holds acc_{t-1} in its own z5 regs (residual A-rows give fp32 accuracy:
//    acc = z5[0]+z5[2]); no cross-lane ops for acc.
//  - U/W/b are UNFOLDED (plain bf16*log2e); the acc correction acc*w-hat*scale
//    is applied to z in fp32 VALU (exact coefficients) — R3/R4 folded it into
//    bf16 U where it was ~2 ulp -> ~30% relative feedback bias x256 steps.
//  - tile-4 gate exchange back to R2-proven __shfl_xor (DPP suspect removed).
// No per-step barrier (same-wave DS ordering, proven by R2).

#define NVEH 16384
#define NT   256
#define H    20

typedef float f32x4  __attribute__((ext_vector_type(4)));
typedef short bf16x8 __attribute__((ext_vector_type(8)));
typedef short bf16x4 __attribute__((ext_vector_type(4)));

#if __has_builtin(__builtin_amdgcn_exp2f)
#define EXP2(x) __builtin_amdgcn_exp2f(x)
#else
#define EXP2(x) __expf((x) * 0.69314718056f)
#endif

__device__ __forceinline__ short f2bf(float f) {     // RNE float->bf16
    unsigned u = __builtin_bit_cast(unsigned, f);
    u += 0x7fffu + ((u >> 16) & 1u);
    return (short)(u >> 16);
}
__device__ __forceinline__ float bf2f(short s) {
    return __builtin_bit_cast(float, ((unsigned)(unsigned short)s) << 16);
}
// sigmoid of a pre-scaled (x*log2e) argument: 1/(1+2^-x)
__device__ __forceinline__ float sig2(float x) {
    return __builtin_amdgcn_rcpf(1.f + EXP2(-x));
}

__global__ __launch_bounds__(256) void rnncf_kernel(
    const float* __restrict__ lead,   // (NVEH, NT, 2)
    const float* __restrict__ inits,  // (NVEH, 2)
    const float* __restrict__ h0,     // (NVEH, H)
    const float* __restrict__ c0,     // (NVEH, H)
    const float* __restrict__ W,      // (3, 80)
    const float* __restrict__ U,      // (20, 80)
    const float* __restrict__ b,      // (80,)
    const float* __restrict__ Wd,     // (20,)
    const float* __restrict__ bd,     // (1,)
    float* __restrict__ out)
{
    // UT cols: 0..63 gates i/f/g/o for j<16 (plain, *log2e; gate g *2log2e);
    // 64..79 j=16..19 gate-interleaved (plain, scaled); 80..95 all identical:
    // bf16(7*Wd) at k<20, bf16(7bd-4) at k=23.
    __shared__ __attribute__((aligned(16))) short UT[96 * 32];
    __shared__ __attribute__((aligned(16))) short aug[4][640];  // 16 rows x 40

    const int tid  = threadIdx.x;
    const int wv   = tid >> 6;
    const int lane = tid & 63;
    const int quad = lane >> 4;       // 0..3
    const int c    = lane & 15;       // MFMA col / j index
    const int s4   = c & 3;
    const int j4   = 16 + (c >> 2);
    const bool own4 = s4 < 2;
    const float L2E = 1.44269504f;

    const float bdv = bd[0];

    // ---- build UT (no folding) ----
    for (int idx = tid; idx < 96 * 32; idx += 256) {
        int colp = idx >> 5, k = idx & 31;
        float v = 0.f;
        if (colp < 80) {
            int gate, j;
            if (colp < 64) { gate = colp >> 4; j = colp & 15; }
            else           { int r = colp - 64; j = 16 + (r >> 2); gate = r & 3; }
            int col = gate * 20 + j;
            if      (k < 20)  v = U[k * 80 + col];
            else if (k < 23)  v = W[(k - 20) * 80 + col];
            else if (k == 23) v = b[col];
            v *= (gate == 2) ? (2.f * L2E) : L2E;
        } else {   // 16 identical acc columns
            if      (k < 20)  v = 7.f * Wd[k];
            else if (k == 23) v = 7.f * bdv - 4.f;
        }
        UT[colp * 32 + k] = f2bf(v);
    }

    const int gveh0 = blockIdx.x * 32 + wv * 8;   // wave's first vehicle
    const int gq    = gveh0 + 2 * quad;           // quad's first vehicle

    // ---- aug init: zero; h rows (4q+s) + residual rows (4q+2+s) ----
    for (int idx = lane; idx < 640; idx += 64) aug[wv][idx] = 0;
    for (int idx = lane; idx < 8 * H; idx += 64) {
        int v8 = idx / H, j = idx - v8 * H;
        int row = 4 * (v8 >> 1) + (v8 & 1);
        float hval = h0[(gveh0 + v8) * H + j];
        short hb = f2bf(hval);
        aug[wv][row * 40 + j] = hb;
        float hi  = bf2f(hb);
        float whj = 7.f * Wd[j];
        float whi = bf2f(f2bf(whj));
        float sj  = (whi != 0.f) ? (whj - whi) * __builtin_amdgcn_rcpf(whi) : 0.f;
        aug[wv][(row + 2) * 40 + j] = f2bf((hval - hi) + hi * sj);
    }

    // ---- per-lane state ----
    float pos[2], spd[2], cst[2], hl[2], hv[2];
#pragma unroll
    for (int s = 0; s < 2; ++s) {
        pos[s] = inits[(gq + s) * 2 + 0];
        spd[s] = inits[(gq + s) * 2 + 1];
        cst[s] = c0[(gq + s) * H + c];
        hv[s]  = h0[(gq + s) * H + c];
        hl[s]  = 0.f;
    }
    float cst4 = own4 ? c0[(gq + s4) * H + j4] : 0.f;
    float hv4  = own4 ? h0[(gq + s4) * H + j4] : 0.f;
    float hl4  = 0.f;
    const float wd_c = Wd[c];
    const float wd_4 = Wd[j4];

    // residual scale for in-loop h writes (col j = c)
    float s_c;
    {
        float whc = 7.f * wd_c, whci = bf2f(f2bf(whc));
        s_c = (whci != 0.f) ? (whc - whci) * __builtin_amdgcn_rcpf(whci) : 0.f;
    }
    float s_4;
    {
        float wh4 = 7.f * wd_4, wh4i = bf2f(f2bf(wh4));
        s_4 = (wh4i != 0.f) ? (wh4 - wh4i) * __builtin_amdgcn_rcpf(wh4i) : 0.f;
    }

    // ---- fp32 feedback coefficients: wc[g] = w-hat[g*20+c]*scale_g ----
    float wc[4], wc4;
#pragma unroll
    for (int g = 0; g < 4; ++g) {
        int col = g * 20 + c;
        wc[g] = (-0.001f * W[col] + 0.0025f * W[80 + col])
              * ((g == 2) ? (2.f * L2E) : L2E);
    }
    {
        int col4 = s4 * 20 + j4;
        wc4 = (-0.001f * W[col4] + 0.0025f * W[80 + col4])
            * ((s4 == 2) ? (2.f * L2E) : L2E);
    }

    // ---- virtual lagged state: pos_{-1} = pos_0 - 0.1*acc_{-1} ----
    {
        float ctb[2] = { hv[0] * wd_c, hv[1] * wd_c };
        if (own4) ctb[s4] += hv4 * wd_4;
        for (int m = 1; m < 16; m <<= 1) {
            ctb[0] += __shfl_xor(ctb[0], m);
            ctb[1] += __shfl_xor(ctb[1], m);
        }
#pragma unroll
        for (int s = 0; s < 2; ++s) {
            float a = 7.f * (ctb[s] + bdv) - 4.f;
            pos[s] -= 0.1f * a;
            spd[s] -= 0.1f * a;
        }
    }

    __syncthreads();   // UT visibility; only barrier in the kernel

    // ---- loop-invariant B fragments (6 tiles) ----
    bf16x8 B[6];
#pragma unroll
    for (int t6 = 0; t6 < 6; ++t6)
        B[t6] = *(const bf16x8*)&UT[(16 * t6 + c) * 32 + quad * 8];

    // ---- x~_0 from virtual state (lane c==0 of each quad) ----
    const float2* lead2 = (const float2*)lead;
    float2 l2a = {0.f, 0.f}, l2b = {0.f, 0.f};
    if (c == 0) {
        l2a = lead2[(long)(gq + 0) * NT];
        l2b = lead2[(long)(gq + 1) * NT];
        bf16x4 x0 = { f2bf((l2a.x - pos[0]) * 0.01f), f2bf(spd[0] * 0.025f),
                      f2bf(l2a.y * 0.025f), f2bf(1.f) };
        bf16x4 x1 = { f2bf((l2b.x - pos[1]) * 0.01f), f2bf(spd[1] * 0.025f),
                      f2bf(l2b.y * 0.025f), f2bf(1.f) };
        *(bf16x4*)&aug[wv][(4 * quad + 0) * 40 + 20] = x0;
        *(bf16x4*)&aug[wv][(4 * quad + 1) * 40 + 20] = x1;
    }

    const int augA = c * 40 + quad * 8;

    for (int t = 0; t < NT; ++t) {
        if (c == 0) {   // prefetch lead[t+1]
            int tn = (t < NT - 1) ? t + 1 : t;
            l2a = lead2[(long)(gq + 0) * NT + tn];
            l2b = lead2[(long)(gq + 1) * NT + tn];
        }

        bf16x8 A = *(const bf16x8*)&aug[wv][augA];
        f32x4 zero = {0.f, 0.f, 0.f, 0.f};
        f32x4 z0 = __builtin_amdgcn_mfma_f32_16x16x32_bf16(A, B[0], zero, 0, 0, 0);
        f32x4 z1 = __builtin_amdgcn_mfma_f32_16x16x32_bf16(A, B[1], zero, 0, 0, 0);
        f32x4 z2 = __builtin_amdgcn_mfma_f32_16x16x32_bf16(A, B[2], zero, 0, 0, 0);
        f32x4 z3 = __builtin_amdgcn_mfma_f32_16x16x32_bf16(A, B[3], zero, 0, 0, 0);
        f32x4 z4 = __builtin_amdgcn_mfma_f32_16x16x32_bf16(A, B[4], zero, 0, 0, 0);
        f32x4 z5 = __builtin_amdgcn_mfma_f32_16x16x32_bf16(A, B[5], zero, 0, 0, 0);

        // ---- acc_{t-1}, fp32-accurate, available on EVERY lane ----
        float acc[2];
        acc[0] = z5[0] + z5[2];
        acc[1] = z5[1] + z5[3];
#pragma unroll
        for (int s = 0; s < 2; ++s) {
            pos[s] += 0.1f * acc[s];
            spd[s] += 0.1f * acc[s];
        }
        if (c == 0) {
            if (t > 0) {
                out[(t - 1) * NVEH + gq + 0] = pos[0];
                out[(t - 1) * NVEH + gq + 1] = pos[1];
            }
            bf16x4 x0 = { f2bf((l2a.x - pos[0]) * 0.01f), f2bf(spd[0] * 0.025f),
                          f2bf(l2a.y * 0.025f), f2bf(1.f) };
            bf16x4 x1 = { f2bf((l2b.x - pos[1]) * 0.01f), f2bf(spd[1] * 0.025f),
                          f2bf(l2b.y * 0.025f), f2bf(1.f) };
            *(bf16x4*)&aug[wv][(4 * quad + 0) * 40 + 20] = x0;
            *(bf16x4*)&aug[wv][(4 * quad + 1) * 40 + 20] = x1;
        }

        // ---- main items: (veh 2q+s, j=c), fp32 feedback correction ----
#pragma unroll
        for (int s = 0; s < 2; ++s) {
            float ii = sig2(z0[s] + acc[s] * wc[0]);
            float ff = sig2(z1[s] + acc[s] * wc[1]);
            float gg = 2.f * sig2(z2[s] + acc[s] * wc[2]) - 1.f;   // tanh(g)
            float oo = sig2(z3[s] + acc[s] * wc[3]);
            float cc = ff * cst[s] + ii * gg;
            cst[s] = cc;
            float hh = oo * (2.f * sig2(2.f * L2E * cc) - 1.f);    // o*tanh(c)
            hl[s] = hh;
            short hb = f2bf(hh);
            aug[wv][(4 * quad + s) * 40 + c] = hb;
            float hi = bf2f(hb);
            aug[wv][(4 * quad + 2 + s) * 40 + c] = f2bf((hh - hi) + hi * s_c);
        }

        // ---- tile 4: correct, nonlin pre-exchange, shfl_xor exchange ----
        {
            float v0 = z4[0] + acc[0] * wc4;
            float v1 = z4[1] + acc[1] * wc4;
            float sg0 = sig2(v0), sg1 = sig2(v1);
            float nl0 = (s4 == 2) ? 2.f * sg0 - 1.f : sg0;
            float nl1 = (s4 == 2) ? 2.f * sg1 - 1.f : sg1;
            // for mask m: send nl[s4^m] (partner's owned-vehicle index)
            float r1 = __shfl_xor(((s4 ^ 1) == 0) ? nl0 : nl1, 1);
            float r2 = __shfl_xor(((s4 ^ 2) == 0) ? nl0 : nl1, 2);
            float r3 = __shfl_xor(((s4 ^ 3) == 0) ? nl0 : nl1, 3);
            float rown = (s4 == 0) ? nl0 : nl1;
#define PICK(mm) ((mm) == 0 ? rown : ((mm) == 1 ? r1 : ((mm) == 2 ? r2 : r3)))
            float i4 = PICK(s4 ^ 0);
            float f4 = PICK(s4 ^ 1);
            float g4 = PICK(s4 ^ 2);
            float o4 = PICK(s4 ^ 3);
#undef PICK
            float c4n = f4 * cst4 + i4 * g4;
            float h4  = o4 * (2.f * sig2(2.f * L2E * c4n) - 1.f);
            if (own4) {
                cst4 = c4n;
                hl4  = h4;
                short hb4 = f2bf(h4);
                aug[wv][(4 * quad + s4) * 40 + j4] = hb4;
                float hi4 = bf2f(hb4);
                aug[wv][(4 * quad + 2 + s4) * 40 + j4] = f2bf((h4 - hi4) + hi4 * s_4);
            }
        }
    }

    // ---- tail: acc_255 via fp32 butterfly -> out[255], final speed ----
    float ctb[2] = { hl[0] * wd_c, hl[1] * wd_c };
    if (own4) ctb[s4] += hl4 * wd_4;
    for (int m = 1; m < 16; m <<= 1) {
        ctb[0] += __shfl_xor(ctb[0], m);
        ctb[1] += __shfl_xor(ctb[1], m);
    }
    if (c == 0) {
#pragma unroll
        for (int s = 0; s < 2; ++s) {
            float a = 7.f * (ctb[s] + bdv) - 4.f;
            out[(NT - 1) * NVEH + gq + s] = pos[s] + 0.1f * a;
            out[NT * NVEH + gq + s]       = spd[s] + 0.1f * a;
        }
    }

    // ---- final h, c ----
    const int oH = NT * NVEH + NVEH;
    const int oC = oH + NVEH * H;
#pragma unroll
    for (int s = 0; s < 2; ++s) {
        out[oH + (gq + s) * H + c] = hl[s];
        out[oC + (gq + s) * H + c] = cst[s];
    }
    if (own4) {
        out[oH + (gq + s4) * H + j4] = hl4;
        out[oC + (gq + s4) * H + j4] = cst4;
    }
}

extern "C" void kernel_launch(void* const* d_in, const int* in_sizes, int n_in,
                              void* d_out, int out_size, void* d_ws, size_t ws_size,
                              hipStream_t stream) {
    const float* lead  = (const float*)d_in[0];
    const float* inits = (const float*)d_in[1];
    const float* h0    = (const float*)d_in[2];
    const float* c0    = (const float*)d_in[3];
    const float* W     = (const float*)d_in[4];
    const float* U     = (const float*)d_in[5];
    const float* b     = (const float*)d_in[6];
    const float* Wd    = (const float*)d_in[7];
    const float* bd    = (const float*)d_in[8];
    float* out = (float*)d_out;

    rnncf_kernel<<<NVEH / 32, 256, 0, stream>>>(lead, inits, h0, c0, W, U, b, Wd, bd, out);
}